// Round 1
// baseline (27.114 us; speedup 1.0000x reference)
//
#include <hip/hip_runtime.h>
#include <hip/hip_fp16.h>

#define BATCH 4
#define HH 1024
#define WW 1024
#define GDp 8
#define NC 12
#define CELL2 7     // half2 per Hs cell: 6 used + 1 pad (28 B) -> odd dw stride
#define HROW2 169   // half2 per Hs row: 24*7 + 1 = 169 dw (169 % 32 == 9)
#define TILEY 32    // rows per block (was 16); halves prologue cost per pixel

typedef float f4 __attribute__((ext_vector_type(4)));

// Tile 64(x) x 32(y), block (16,32)=512 threads, 4 px/thread.
// Same VGPR footprint as the 16-row version; occupancy unchanged
// (2 blocks/CU x 8 waves = 16 waves/CU, LDS 25 KB/block -> 50 KB/CU).
__global__ __launch_bounds__(512, 4) void bsa_kernel(
    const float* __restrict__ grid,
    const float* __restrict__ guide,
    const float* __restrict__ image,
    float* __restrict__ out)
{
    __shared__ float   sg[GDp][3][3][NC];      // o-pack-permuted channels, f32 (3456 B)
    __shared__ __half2 Hs2[TILEY][HROW2];      // y-preinterp, f16, odd-stride (21632 B)

    const int bx = blockIdx.x;   // 0..15
    const int by = blockIdx.y;   // 0..31
    const int b  = blockIdx.z;
    const int tx = threadIdx.x;  // 0..15
    const int ty = threadIdx.y;  // 0..31
    const int tid = ty * 16 + tx;

    const int x0 = bx * 64;
    const int y0 = by * TILEY;
    const float inv64 = 1.0f / 64.0f;

    // 32 rows span 31/64 < 1 grid cell in y -> floor(gy) in {ylo, ylo+1},
    // so the 3-cell y staging (ys0 in {0,1}, +1 neighbor) still covers it.
    const float gy0 = (y0 + 0.5f) * inv64 - 0.5f;
    const int ylo = (int)floorf(gy0);

    // ---- issue pixel IO early: latency hides under staging + barriers ----
    // guide/image/out are touched exactly once -> nontemporal (don't thrash
    // L2; keep the 786 KB grid resident instead).
    const int y = y0 + ty;
    const int xloc = 4 * tx;
    const size_t plane = (size_t)HH * WW;
    const size_t gpix = ((size_t)(b * HH + y)) * WW + x0 + xloc;
    const size_t ib   = (size_t)b * 3 * plane + (size_t)y * WW + x0 + xloc;
    const f4 g4  = __builtin_nontemporal_load((const f4*)&guide[gpix]);
    const f4 im0 = __builtin_nontemporal_load((const f4*)&image[ib]);
    const f4 im1 = __builtin_nontemporal_load((const f4*)&image[ib + plane]);
    const f4 im2 = __builtin_nontemporal_load((const f4*)&image[ib + 2 * plane]);

    // ---- stage grid slice: div-free, one shot, o-pack channel permute ----
    if (tid < 256) {
        const int z = tid >> 5;        // 0..7
        const int u = tid & 31;        // active u<27
        if (u < 27) {
            const int cell = (u * 11) >> 5;      // u/3 (exact for u<32)
            const int cq   = u - cell * 3;       // u%3 -> channel quad
            const int yy   = (cell * 11) >> 5;   // cell/3 (exact, cell<9)
            const int xx   = cell - yy * 3;
            const int gxi = min(max(bx - 1 + xx, 0), 15);
            const int gyi = min(max(ylo + yy, 0), 15);
            const float* gp = grid + (size_t)b * (NC * GDp * 256)
                                   + ((size_t)z * 16 + gyi) * 16 + gxi;
#pragma unroll
            for (int j = 0; j < 4; ++j) {
                const int c = cq * 4 + j;
                // o-pack perm: pairs (c0,c4)(c1,c5)(c2,c6)(c3,c7)(c8,c9)(c10,c11)
                const int pos = (c < 8) ? ((c & 3) * 2 + (c >> 2)) : c;
                sg[z][yy][xx][pos] = gp[(size_t)c * (GDp * 256)];
            }
        }
    }
    __syncthreads();

    // ---- Hs build: 768 entries, e = cell*32 + r; writes spread all banks ----
    for (int e = tid; e < 24 * TILEY; e += 512) {
        const int r    = e & (TILEY - 1);
        const int cell = e >> 5;        // 0..23 = xs*8 + z
        const int xs   = cell >> 3;
        const int z    = cell & 7;
        const float gy  = (y0 + r + 0.5f) * inv64 - 0.5f;
        const float fyf = floorf(gy);
        const float wy1 = gy - fyf;
        const float wy0 = 1.0f - wy1;
        const int ys0 = (int)fyf - ylo;          // 0 or 1
        const float* s0 = &sg[z][ys0][xs][0];
        const float* s1 = &sg[z][ys0 + 1][xs][0];
        __half2* hd = &Hs2[r][cell * CELL2];
#pragma unroll
        for (int m = 0; m < 6; ++m) {
            hd[m] = __floats2half2_rn(wy0 * s0[2*m]   + wy1 * s1[2*m],
                                      wy0 * s0[2*m+1] + wy1 * s1[2*m+1]);
        }
    }
    __syncthreads();

    // ---- per-pixel: 4 adjacent x px/thread ----
    const int xs0 = tx >> 3;                     // 0 (x<32) or 1
    const float fxf = (float)(bx - 1 + xs0);
    const float gxb = (x0 + xloc + 0.5f) * inv64 - 0.5f;
    const __half2* Hrow = &Hs2[ty][0];

    const float gk[4]  = {g4.x, g4.y, g4.z, g4.w};
    const float ia[4]  = {im0.x, im0.y, im0.z, im0.w};
    const float ja[4]  = {im1.x, im1.y, im1.z, im1.w};
    const float ka[4]  = {im2.x, im2.y, im2.z, im2.w};
    float ok0[4], ok1[4], ok2[4];

#pragma unroll
    for (int k = 0; k < 4; ++k) {
        const float wx1 = (gxb - fxf) + (float)k * inv64;
        const float wx0 = 1.0f - wx1;

        const float gz  = fmaf(gk[k], 8.0f, -0.5f);
        const float fzf = floorf(gz);
        const float zpf = fminf(fmaxf(fzf, 0.0f), 6.0f);      // v_med3
        const float whi = fminf(fmaxf(gz - zpf, 0.0f), 1.0f); // v_med3
        const float wlo = 1.0f - whi;
        const int zp = (int)zpf;

        const __half2 w00 = __float2half2_rn(wx0 * wlo);
        const __half2 w10 = __float2half2_rn(wx0 * whi);
        const __half2 w01 = __float2half2_rn(wx1 * wlo);
        const __half2 w11 = __float2half2_rn(wx1 * whi);

        // one base addr; all 24 b32 reads at compile-time offsets
        const __half2* q = Hrow + (xs0 * 8 + zp) * CELL2;
        const __half2 A0 = q[0],  A1 = q[1],  A2 = q[2],  A3 = q[3],  A4 = q[4],  A5 = q[5];
        const __half2 B0 = q[7],  B1 = q[8],  B2 = q[9],  B3 = q[10], B4 = q[11], B5 = q[12];
        const __half2 C0 = q[56], C1 = q[57], C2 = q[58], C3 = q[59], C4 = q[60], C5 = q[61];
        const __half2 D0 = q[63], D1 = q[64], D2 = q[65], D3 = q[66], D4 = q[67], D5 = q[68];

        const __half2 r0 = __hfma2(w00, A0, __hfma2(w10, B0, __hfma2(w01, C0, __hmul2(w11, D0))));
        const __half2 r1 = __hfma2(w00, A1, __hfma2(w10, B1, __hfma2(w01, C1, __hmul2(w11, D1))));
        const __half2 r2 = __hfma2(w00, A2, __hfma2(w10, B2, __hfma2(w01, C2, __hmul2(w11, D2))));
        const __half2 r3 = __hfma2(w00, A3, __hfma2(w10, B3, __hfma2(w01, C3, __hmul2(w11, D3))));
        const __half2 r4 = __hfma2(w00, A4, __hfma2(w10, B4, __hfma2(w01, C4, __hmul2(w11, D4))));
        const __half2 r5 = __hfma2(w00, A5, __hfma2(w10, B5, __hfma2(w01, C5, __hmul2(w11, D5))));
        // r0=(A00,A10) r1=(A01,A11) r2=(A02,A12) r3=(A03,A13) r4=(A20,A21) r5=(A22,A23)

        // broadcast/pair image values directly via cvt_pkrtz (saves cvt+pack chains)
        const __half2 bi0 = __float2half2_rn(ia[k]);
        const __half2 bi1 = __float2half2_rn(ja[k]);
        const __half2 bi2 = __float2half2_rn(ka[k]);
        const __half2 p01 = __floats2half2_rn(ia[k], ja[k]);   // (i0, i1)
        const __half2 p21 = __floats2half2_rn(ka[k], 1.0f);    // (i2, 1)

        const __half2 acc01 = __hfma2(bi0, r0, __hfma2(bi1, r1, __hfma2(bi2, r2, r3)));
        const __half2 d2 = __hfma2(p01, r4, __hmul2(p21, r5));

        ok0[k] = __low2float(acc01);
        ok1[k] = __high2float(acc01);
        ok2[k] = __half2float(__hadd(__low2half(d2), __high2half(d2)));
    }

    const f4 o0 = {ok0[0], ok0[1], ok0[2], ok0[3]};
    const f4 o1 = {ok1[0], ok1[1], ok1[2], ok1[3]};
    const f4 o2 = {ok2[0], ok2[1], ok2[2], ok2[3]};
    __builtin_nontemporal_store(o0, (f4*)&out[ib]);
    __builtin_nontemporal_store(o1, (f4*)&out[ib + plane]);
    __builtin_nontemporal_store(o2, (f4*)&out[ib + 2 * plane]);
}

extern "C" void kernel_launch(void* const* d_in, const int* in_sizes, int n_in,
                              void* d_out, int out_size, void* d_ws, size_t ws_size,
                              hipStream_t stream) {
    const float* grid  = (const float*)d_in[0];
    const float* guide = (const float*)d_in[1];
    const float* image = (const float*)d_in[2];
    float* out = (float*)d_out;

    dim3 block(16, 32, 1);
    dim3 grid_dim(WW / 64, HH / TILEY, BATCH);
    bsa_kernel<<<grid_dim, block, 0, stream>>>(grid, guide, image, out);
}

// Round 2
// 25.055 us; speedup vs baseline: 1.0822x; 1.0822x over previous
//
#include <hip/hip_runtime.h>
#include <hip/hip_fp16.h>

#define BATCH 4
#define HH 1024
#define WW 1024
#define GDp 8
#define NC 12
#define PAIR2 12    // half2 per z-pair cell: cells (z=p, z=p+1), 48 B, 16-B aligned
#define NPAIR 21    // 3 xs * 7 pairs
#define HROW2 268   // half2 per Hs row: 21*12=252 used, pad to 268 (268%32==12)

typedef float f4 __attribute__((ext_vector_type(4)));
union V4 { int4 i4; __half2 h[4]; };

// Tile 64(x) x 16(y), block (16,16), 4 px/thread. (round-0 verified structure;
// only the Hs layout/read path changed: z-pair cells + ds_read_b128)
__global__ __launch_bounds__(256, 4) void bsa_kernel(
    const float* __restrict__ grid,
    const float* __restrict__ guide,
    const float* __restrict__ image,
    float* __restrict__ out)
{
    __shared__ float sg[GDp][3][3][NC];                  // o-pack-permuted, f32 (3456 B)
    __shared__ __align__(16) __half2 Hs2[16][HROW2];     // y-preinterp z-pairs (17152 B)

    const int bx = blockIdx.x;   // 0..15
    const int by = blockIdx.y;   // 0..63
    const int b  = blockIdx.z;
    const int tx = threadIdx.x;  // 0..15
    const int ty = threadIdx.y;  // 0..15
    const int tid = ty * 16 + tx;

    const int x0 = bx * 64;
    const int y0 = by * 16;
    const float inv64 = 1.0f / 64.0f;

    const float gy0 = (y0 + 0.5f) * inv64 - 0.5f;
    const int ylo = (int)floorf(gy0);

    // ---- issue pixel IO early: latency hides under staging + barriers ----
    const int y = y0 + ty;
    const int xloc = 4 * tx;
    const size_t plane = (size_t)HH * WW;
    const size_t gpix = ((size_t)(b * HH + y)) * WW + x0 + xloc;
    const size_t ib   = (size_t)b * 3 * plane + (size_t)y * WW + x0 + xloc;
    const float4 g4  = *(const float4*)&guide[gpix];
    const float4 im0 = *(const float4*)&image[ib];
    const float4 im1 = *(const float4*)&image[ib + plane];
    const float4 im2 = *(const float4*)&image[ib + 2 * plane];

    // ---- stage grid slice: div-free, one shot, o-pack channel permute ----
    {
        const int z = tid >> 5;        // 0..7
        const int u = tid & 31;        // active u<27
        if (u < 27) {
            const int cell = (u * 11) >> 5;      // u/3 (exact for u<32)
            const int cq   = u - cell * 3;       // u%3 -> channel quad
            const int yy   = (cell * 11) >> 5;   // cell/3 (exact, cell<9)
            const int xx   = cell - yy * 3;
            const int gxi = min(max(bx - 1 + xx, 0), 15);
            const int gyi = min(max(ylo + yy, 0), 15);
            const float* gp = grid + (size_t)b * (NC * GDp * 256)
                                   + ((size_t)z * 16 + gyi) * 16 + gxi;
#pragma unroll
            for (int j = 0; j < 4; ++j) {
                const int c = cq * 4 + j;
                // o-pack perm: pairs (c0,c4)(c1,c5)(c2,c6)(c3,c7)(c8,c9)(c10,c11)
                const int pos = (c < 8) ? ((c & 3) * 2 + (c >> 2)) : c;
                sg[z][yy][xx][pos] = gp[(size_t)c * (GDp * 256)];
            }
        }
    }
    __syncthreads();

    // ---- Hs build: 384 (r, xs, z) cells; each written into z-pairs (z-1,z) & (z,z+1)
    for (int e = tid; e < 384; e += 256) {
        const int r    = e & 15;
        const int cell = e >> 4;        // 0..23 = xs*8 + z
        const int xs   = cell >> 3;
        const int z    = cell & 7;
        const float gy  = (y0 + r + 0.5f) * inv64 - 0.5f;
        const float fyf = floorf(gy);
        const float wy1 = gy - fyf;
        const float wy0 = 1.0f - wy1;
        const int ys0 = (int)fyf - ylo;          // 0 or 1
        const float* s0 = &sg[z][ys0][xs][0];
        const float* s1 = &sg[z][ys0 + 1][xs][0];
        __half2 h[6];
#pragma unroll
        for (int m = 0; m < 6; ++m) {
            h[m] = __floats2half2_rn(wy0 * s0[2*m]   + wy1 * s1[2*m],
                                     wy0 * s0[2*m+1] + wy1 * s1[2*m+1]);
        }
        __half2* rowp = &Hs2[r][0];
        if (z < 7) {                 // first half of pair p=z
            __half2* hd = rowp + (xs * 7 + z) * PAIR2;
#pragma unroll
            for (int m = 0; m < 6; ++m) hd[m] = h[m];
        }
        if (z > 0) {                 // second half of pair p=z-1
            __half2* hd = rowp + (xs * 7 + (z - 1)) * PAIR2 + 6;
#pragma unroll
            for (int m = 0; m < 6; ++m) hd[m] = h[m];
        }
    }
    __syncthreads();

    // ---- per-pixel: 4 adjacent x px/thread ----
    const int xs0 = tx >> 3;                     // 0 (x<32) or 1
    const float fxf = (float)(bx - 1 + xs0);
    const float gxb = (x0 + xloc + 0.5f) * inv64 - 0.5f;
    const __half2* Hrow = &Hs2[ty][0];

    const float gk[4]  = {g4.x, g4.y, g4.z, g4.w};
    const float ia[4]  = {im0.x, im0.y, im0.z, im0.w};
    const float ja[4]  = {im1.x, im1.y, im1.z, im1.w};
    const float ka[4]  = {im2.x, im2.y, im2.z, im2.w};
    float ok0[4], ok1[4], ok2[4];

    const __half oneh = __float2half_rn(1.0f);

#pragma unroll
    for (int k = 0; k < 4; ++k) {
        const float wx1 = (gxb - fxf) + (float)k * inv64;
        const float wx0 = 1.0f - wx1;

        const float gz  = fmaf(gk[k], 8.0f, -0.5f);
        const float fzf = floorf(gz);
        const float zpf = fminf(fmaxf(fzf, 0.0f), 6.0f);      // v_med3
        const float whi = fminf(fmaxf(gz - zpf, 0.0f), 1.0f); // v_med3
        const float wlo = 1.0f - whi;
        const int zp = (int)zpf;

        const __half2 w00 = __float2half2_rn(wx0 * wlo);
        const __half2 w10 = __float2half2_rn(wx0 * whi);
        const __half2 w01 = __float2half2_rn(wx1 * wlo);
        const __half2 w11 = __float2half2_rn(wx1 * whi);

        // z-pair layout: 6 aligned ds_read_b128 cover all 4 corners
        const __half2* q = Hrow + (xs0 * 7 + zp) * PAIR2;
        V4 va, vb, vc, vd, ve, vf;
        va.i4 = *(const int4*)(q);           // A0..A3
        vb.i4 = *(const int4*)(q + 4);       // A4,A5,B0,B1
        vc.i4 = *(const int4*)(q + 8);       // B2..B5
        vd.i4 = *(const int4*)(q + 7 * PAIR2);     // C0..C3
        ve.i4 = *(const int4*)(q + 7 * PAIR2 + 4); // C4,C5,D0,D1
        vf.i4 = *(const int4*)(q + 7 * PAIR2 + 8); // D2..D5

        const __half2 A0 = va.h[0], A1 = va.h[1], A2 = va.h[2], A3 = va.h[3];
        const __half2 A4 = vb.h[0], A5 = vb.h[1];
        const __half2 B0 = vb.h[2], B1 = vb.h[3];
        const __half2 B2 = vc.h[0], B3 = vc.h[1], B4 = vc.h[2], B5 = vc.h[3];
        const __half2 C0 = vd.h[0], C1 = vd.h[1], C2 = vd.h[2], C3 = vd.h[3];
        const __half2 C4 = ve.h[0], C5 = ve.h[1];
        const __half2 D0 = ve.h[2], D1 = ve.h[3];
        const __half2 D2 = vf.h[0], D3 = vf.h[1], D4 = vf.h[2], D5 = vf.h[3];

        const __half2 r0 = __hfma2(w00, A0, __hfma2(w10, B0, __hfma2(w01, C0, __hmul2(w11, D0))));
        const __half2 r1 = __hfma2(w00, A1, __hfma2(w10, B1, __hfma2(w01, C1, __hmul2(w11, D1))));
        const __half2 r2 = __hfma2(w00, A2, __hfma2(w10, B2, __hfma2(w01, C2, __hmul2(w11, D2))));
        const __half2 r3 = __hfma2(w00, A3, __hfma2(w10, B3, __hfma2(w01, C3, __hmul2(w11, D3))));
        const __half2 r4 = __hfma2(w00, A4, __hfma2(w10, B4, __hfma2(w01, C4, __hmul2(w11, D4))));
        const __half2 r5 = __hfma2(w00, A5, __hfma2(w10, B5, __hfma2(w01, C5, __hmul2(w11, D5))));
        // r0=(A00,A10) r1=(A01,A11) r2=(A02,A12) r3=(A03,A13) r4=(A20,A21) r5=(A22,A23)

        const __half i0h = __float2half_rn(ia[k]);
        const __half i1h = __float2half_rn(ja[k]);
        const __half i2h = __float2half_rn(ka[k]);
        const __half2 bi0 = __half2half2(i0h);
        const __half2 bi1 = __half2half2(i1h);
        const __half2 bi2 = __half2half2(i2h);

        const __half2 acc01 = __hfma2(bi0, r0, __hfma2(bi1, r1, __hfma2(bi2, r2, r3)));
        const __half2 d2 = __hfma2(__halves2half2(i0h, i1h), r4,
                                   __hmul2(__halves2half2(i2h, oneh), r5));

        ok0[k] = __low2float(acc01);
        ok1[k] = __high2float(acc01);
        ok2[k] = __half2float(__hadd(__low2half(d2), __high2half(d2)));
    }

    *(float4*)&out[ib]             = make_float4(ok0[0], ok0[1], ok0[2], ok0[3]);
    *(float4*)&out[ib + plane]     = make_float4(ok1[0], ok1[1], ok1[2], ok1[3]);
    *(float4*)&out[ib + 2 * plane] = make_float4(ok2[0], ok2[1], ok2[2], ok2[3]);
}

extern "C" void kernel_launch(void* const* d_in, const int* in_sizes, int n_in,
                              void* d_out, int out_size, void* d_ws, size_t ws_size,
                              hipStream_t stream) {
    const float* grid  = (const float*)d_in[0];
    const float* guide = (const float*)d_in[1];
    const float* image = (const float*)d_in[2];
    float* out = (float*)d_out;

    dim3 block(16, 16, 1);
    dim3 grid_dim(WW / 64, HH / 16, BATCH);
    bsa_kernel<<<grid_dim, block, 0, stream>>>(grid, guide, image, out);
}

// Round 3
// 24.888 us; speedup vs baseline: 1.0894x; 1.0067x over previous
//
#include <hip/hip_runtime.h>
#include <hip/hip_fp16.h>

#define BATCH 4
#define HH 1024
#define WW 1024
#define GDp 8
#define NC 12
#define PAIR2 12    // half2 per z-pair cell: cells (z=p, z=p+1), 48 B, 16-B aligned
#define HROW2 268   // half2 per Hs row: 21*12=252 used, pad to 268 (268%32==12)
#define NTILE 4     // 64x16 tiles per block (one 64x64 column)

union V4 { int4 i4; __half2 h[4]; };

// Persistent column: block (16,16)=256 thr owns 64(x) x 64(y) pixels as 4
// pipelined 64x16 tiles. 1024 blocks = exactly 4 resident/CU.
// sg staged ONCE (64 rows span <1 grid cell in y -> same 3x3 cell footprint);
// Hs double-buffered; next tile's pixel IO prefetched during current compute.
__global__ __launch_bounds__(256, 4) void bsa_kernel(
    const float* __restrict__ grid,
    const float* __restrict__ guide,
    const float* __restrict__ image,
    float* __restrict__ out)
{
    __shared__ float sg[GDp][3][3][NC];                     // 3456 B
    __shared__ __align__(16) __half2 Hs2[2][16][HROW2];     // 2 x 17152 B

    const int bx  = blockIdx.x;   // 0..15
    const int byc = blockIdx.y;   // 0..15  (64-row column)
    const int b   = blockIdx.z;
    const int tx = threadIdx.x;   // 0..15
    const int ty = threadIdx.y;   // 0..15
    const int tid = ty * 16 + tx;

    const int x0  = bx * 64;
    const int y0c = byc * 64;
    const float inv64 = 1.0f / 64.0f;

    // Column y-cell base: rows y0c..y0c+63 have floor(gy) in {ylo, ylo+1},
    // so cells ylo..ylo+2 (3 rows) cover every tile's Hs build.
    const float gy0c = (y0c + 0.5f) * inv64 - 0.5f;
    const int ylo = (int)floorf(gy0c);

    const int xloc = 4 * tx;
    const size_t plane = (size_t)HH * WW;
    const size_t gpix0 = ((size_t)(b * HH + y0c + ty)) * WW + x0 + xloc;
    const size_t ib0   = (size_t)b * 3 * plane + (size_t)(y0c + ty) * WW + x0 + xloc;

    // ---- tile-0 pixel IO: in flight under staging + Hs build ----
    float4 cg  = *(const float4*)&guide[gpix0];
    float4 ci0 = *(const float4*)&image[ib0];
    float4 ci1 = *(const float4*)&image[ib0 + plane];
    float4 ci2 = *(const float4*)&image[ib0 + 2 * plane];

    // ---- stage grid slice once per block: o-pack channel permute ----
    {
        const int z = tid >> 5;        // 0..7
        const int u = tid & 31;        // active u<27
        if (u < 27) {
            const int cell = (u * 11) >> 5;      // u/3 (exact for u<32)
            const int cq   = u - cell * 3;       // u%3 -> channel quad
            const int yy   = (cell * 11) >> 5;   // cell/3 (exact, cell<9)
            const int xx   = cell - yy * 3;
            const int gxi = min(max(bx - 1 + xx, 0), 15);
            const int gyi = min(max(ylo + yy, 0), 15);
            const float* gp = grid + (size_t)b * (NC * GDp * 256)
                                   + ((size_t)z * 16 + gyi) * 16 + gxi;
#pragma unroll
            for (int j = 0; j < 4; ++j) {
                const int c = cq * 4 + j;
                // o-pack perm: pairs (c0,c4)(c1,c5)(c2,c6)(c3,c7)(c8,c9)(c10,c11)
                const int pos = (c < 8) ? ((c & 3) * 2 + (c >> 2)) : c;
                sg[z][yy][xx][pos] = gp[(size_t)c * (GDp * 256)];
            }
        }
    }
    __syncthreads();

    // ---- Hs build for one 16-row tile into buffer buf ----
    auto build_hs = [&](int buf, int t) {
        for (int e = tid; e < 384; e += 256) {
            const int r    = e & 15;
            const int cell = e >> 4;        // 0..23 = xs*8 + z
            const int xs   = cell >> 3;
            const int z    = cell & 7;
            const float gy  = (y0c + t * 16 + r + 0.5f) * inv64 - 0.5f;
            const float fyf = floorf(gy);
            const float wy1 = gy - fyf;
            const float wy0 = 1.0f - wy1;
            const int ys0 = (int)fyf - ylo;          // 0 or 1 (column-wide)
            const float* s0 = &sg[z][ys0][xs][0];
            const float* s1 = &sg[z][ys0 + 1][xs][0];
            __half2 h[6];
#pragma unroll
            for (int m = 0; m < 6; ++m) {
                h[m] = __floats2half2_rn(wy0 * s0[2*m]   + wy1 * s1[2*m],
                                         wy0 * s0[2*m+1] + wy1 * s1[2*m+1]);
            }
            __half2* rowp = &Hs2[buf][r][0];
            if (z < 7) {                 // first half of pair p=z
                __half2* hd = rowp + (xs * 7 + z) * PAIR2;
#pragma unroll
                for (int m = 0; m < 6; ++m) hd[m] = h[m];
            }
            if (z > 0) {                 // second half of pair p=z-1
                __half2* hd = rowp + (xs * 7 + (z - 1)) * PAIR2 + 6;
#pragma unroll
                for (int m = 0; m < 6; ++m) hd[m] = h[m];
            }
        }
    };

    build_hs(0, 0);
    __syncthreads();

    const int xs0 = tx >> 3;                     // 0 (x<32) or 1
    const float fxf = (float)(bx - 1 + xs0);
    const float gxb = (x0 + xloc + 0.5f) * inv64 - 0.5f;
    const __half oneh = __float2half_rn(1.0f);

#pragma unroll
    for (int t = 0; t < NTILE; ++t) {
        // ---- prefetch next tile's pixel IO: stays in flight across compute ----
        float4 ng, ni0, ni1, ni2;
        if (t < NTILE - 1) {
            const size_t gp  = gpix0 + (size_t)(t + 1) * 16 * WW;
            const size_t ibn = ib0   + (size_t)(t + 1) * 16 * WW;
            ng  = *(const float4*)&guide[gp];
            ni0 = *(const float4*)&image[ibn];
            ni1 = *(const float4*)&image[ibn + plane];
            ni2 = *(const float4*)&image[ibn + 2 * plane];
        }

        // ---- per-pixel compute: 4 adjacent x px/thread ----
        const __half2* Hrow = &Hs2[t & 1][ty][0];
        const size_t ib = ib0 + (size_t)t * 16 * WW;

        const float gk[4]  = {cg.x, cg.y, cg.z, cg.w};
        const float ia[4]  = {ci0.x, ci0.y, ci0.z, ci0.w};
        const float ja[4]  = {ci1.x, ci1.y, ci1.z, ci1.w};
        const float ka[4]  = {ci2.x, ci2.y, ci2.z, ci2.w};
        float ok0[4], ok1[4], ok2[4];

#pragma unroll
        for (int k = 0; k < 4; ++k) {
            const float wx1 = (gxb - fxf) + (float)k * inv64;
            const float wx0 = 1.0f - wx1;

            const float gz  = fmaf(gk[k], 8.0f, -0.5f);
            const float fzf = floorf(gz);
            const float zpf = fminf(fmaxf(fzf, 0.0f), 6.0f);      // v_med3
            const float whi = fminf(fmaxf(gz - zpf, 0.0f), 1.0f); // v_med3
            const float wlo = 1.0f - whi;
            const int zp = (int)zpf;

            const __half2 w00 = __float2half2_rn(wx0 * wlo);
            const __half2 w10 = __float2half2_rn(wx0 * whi);
            const __half2 w01 = __float2half2_rn(wx1 * wlo);
            const __half2 w11 = __float2half2_rn(wx1 * whi);

            // z-pair layout: 6 aligned ds_read_b128 cover all 4 corners
            const __half2* q = Hrow + (xs0 * 7 + zp) * PAIR2;
            V4 va, vb, vc, vd, ve, vf;
            va.i4 = *(const int4*)(q);           // A0..A3
            vb.i4 = *(const int4*)(q + 4);       // A4,A5,B0,B1
            vc.i4 = *(const int4*)(q + 8);       // B2..B5
            vd.i4 = *(const int4*)(q + 7 * PAIR2);     // C0..C3
            ve.i4 = *(const int4*)(q + 7 * PAIR2 + 4); // C4,C5,D0,D1
            vf.i4 = *(const int4*)(q + 7 * PAIR2 + 8); // D2..D5

            const __half2 A0 = va.h[0], A1 = va.h[1], A2 = va.h[2], A3 = va.h[3];
            const __half2 A4 = vb.h[0], A5 = vb.h[1];
            const __half2 B0 = vb.h[2], B1 = vb.h[3];
            const __half2 B2 = vc.h[0], B3 = vc.h[1], B4 = vc.h[2], B5 = vc.h[3];
            const __half2 C0 = vd.h[0], C1 = vd.h[1], C2 = vd.h[2], C3 = vd.h[3];
            const __half2 C4 = ve.h[0], C5 = ve.h[1];
            const __half2 D0 = ve.h[2], D1 = ve.h[3];
            const __half2 D2 = vf.h[0], D3 = vf.h[1], D4 = vf.h[2], D5 = vf.h[3];

            const __half2 r0 = __hfma2(w00, A0, __hfma2(w10, B0, __hfma2(w01, C0, __hmul2(w11, D0))));
            const __half2 r1 = __hfma2(w00, A1, __hfma2(w10, B1, __hfma2(w01, C1, __hmul2(w11, D1))));
            const __half2 r2 = __hfma2(w00, A2, __hfma2(w10, B2, __hfma2(w01, C2, __hmul2(w11, D2))));
            const __half2 r3 = __hfma2(w00, A3, __hfma2(w10, B3, __hfma2(w01, C3, __hmul2(w11, D3))));
            const __half2 r4 = __hfma2(w00, A4, __hfma2(w10, B4, __hfma2(w01, C4, __hmul2(w11, D4))));
            const __half2 r5 = __hfma2(w00, A5, __hfma2(w10, B5, __hfma2(w01, C5, __hmul2(w11, D5))));
            // r0=(A00,A10) r1=(A01,A11) r2=(A02,A12) r3=(A03,A13) r4=(A20,A21) r5=(A22,A23)

            const __half i0h = __float2half_rn(ia[k]);
            const __half i1h = __float2half_rn(ja[k]);
            const __half i2h = __float2half_rn(ka[k]);
            const __half2 bi0 = __half2half2(i0h);
            const __half2 bi1 = __half2half2(i1h);
            const __half2 bi2 = __half2half2(i2h);

            const __half2 acc01 = __hfma2(bi0, r0, __hfma2(bi1, r1, __hfma2(bi2, r2, r3)));
            const __half2 d2 = __hfma2(__halves2half2(i0h, i1h), r4,
                                       __hmul2(__halves2half2(i2h, oneh), r5));

            ok0[k] = __low2float(acc01);
            ok1[k] = __high2float(acc01);
            ok2[k] = __half2float(__hadd(__low2half(d2), __high2half(d2)));
        }

        *(float4*)&out[ib]             = make_float4(ok0[0], ok0[1], ok0[2], ok0[3]);
        *(float4*)&out[ib + plane]     = make_float4(ok1[0], ok1[1], ok1[2], ok1[3]);
        *(float4*)&out[ib + 2 * plane] = make_float4(ok2[0], ok2[1], ok2[2], ok2[3]);

        // ---- build next tile's Hs into the other buffer (no conflict with
        // this tile's reads; barrier below publishes it for iteration t+1) ----
        if (t < NTILE - 1) {
            build_hs((t + 1) & 1, t + 1);
            __syncthreads();
            cg = ng; ci0 = ni0; ci1 = ni1; ci2 = ni2;
        }
    }
}

extern "C" void kernel_launch(void* const* d_in, const int* in_sizes, int n_in,
                              void* d_out, int out_size, void* d_ws, size_t ws_size,
                              hipStream_t stream) {
    const float* grid  = (const float*)d_in[0];
    const float* guide = (const float*)d_in[1];
    const float* image = (const float*)d_in[2];
    float* out = (float*)d_out;

    dim3 block(16, 16, 1);
    dim3 grid_dim(WW / 64, HH / 64, BATCH);
    bsa_kernel<<<grid_dim, block, 0, stream>>>(grid, guide, image, out);
}